// Round 14
// baseline (156.047 us; speedup 1.0000x reference)
//
#include <hip/hip_runtime.h>
#include <hip/hip_bf16.h>
#include <stdint.h>

typedef __attribute__((ext_vector_type(16))) float f32x16;
typedef __attribute__((ext_vector_type(4)))  float f32x4;
typedef __attribute__((ext_vector_type(4), aligned(4))) float f32x4u;  // 4B-aligned vec load
typedef __attribute__((ext_vector_type(8)))  __bf16 bf16x8;

#define CIN 64
#define HW 96
#define PW 98
#define OCH 128
#define NF 54
#define PCH (PW*PW)            // 9604
#define PIMG (CIN*PCH)         // 614656
#define PAD_FLOATS (8*PIMG)    // 4917248
#define PAD_BYTES ((size_t)PAD_FLOATS*4)
#define CHB 16384              // bytes per channel weight slab (128 oc x 64 k x 2B)
#define WB_BYTES ((size_t)CIN*CHB)   // 1 MiB

// ---------- pad x: [8][64][96][96] -> [8][64][98][98] zero-rimmed
__global__ __launch_bounds__(256) void prep_pad(const float* __restrict__ x,
                                                float* __restrict__ xp) {
    int idx = blockIdx.x*256 + threadIdx.x;    // grid sized exactly
    int pw_ = idx % PW;
    int t   = idx / PW;
    int ph  = t % PW;
    int ic  = t / PW;
    int h = ph - 1, w = pw_ - 1;
    float v = (((unsigned)h < HW) & ((unsigned)w < HW))
            ? x[(size_t)ic*(HW*HW) + h*HW + w] : 0.f;
    xp[idx] = v;
}

// ---------- weight prep: fp32 [oc 128][c 64][54] -> bf16 fragment-native
// elem index = ((c*4 + kc)*2 + hi)*1024 + oc*8 + i   (k = kc*16 + hi*8 + i)
__global__ __launch_bounds__(256) void prep_w(const float* __restrict__ w,
                                              __bf16* __restrict__ wb) {
    int idx = blockIdx.x * 256 + threadIdx.x;   // 262144
    int j  = idx & 31;
    int oc = (idx >> 5) & 127;
    int c  = idx >> 12;
    int k  = 2 * j;
    int kc = k >> 4, hi = (k >> 3) & 1, i = k & 7;
    float v0 = (k     < NF) ? w[(oc*CIN + c)*NF + k    ] : 0.f;
    float v1 = (k + 1 < NF) ? w[(oc*CIN + c)*NF + k + 1] : 0.f;
    size_t off = ((size_t)(c*8 + kc*2 + hi))*1024 + oc*8 + i;
    union { __bf16 b[2]; uint32_t u; } pk;
    pk.b[0] = (__bf16)v0; pk.b[1] = (__bf16)v1;
    *(uint32_t*)((char*)wb + off*2) = pk.u;
}

// cross-product pair tables (PM_cross order)
__device__ __forceinline__ constexpr int PIc(int k) {
    constexpr int t[36] = {0,1,2,3,4,5,6,7, 0,1,2,3,4,5,6, 0,1,2,3,4,5,
                           0,1,2,3,4, 0,1,2,3, 0,1,2, 0,1, 0};
    return t[k];
}
__device__ __forceinline__ constexpr int PJc(int k) {
    constexpr int t[36] = {1,2,3,4,5,6,7,8, 2,3,4,5,6,7,8, 3,4,5,6,7,8,
                           4,5,6,7,8, 5,6,7,8, 6,7,8, 7,8, 8};
    return t[k];
}

// runtime k, fully constant-folds under #pragma unroll
__device__ __forceinline__ float featv(int k, const float* q) {
    return (k < 9)  ? q[k]
         : (k < 18) ? q[k-9] * q[k-9]
         : (k < 54) ? q[PIc(k-18)] * q[PJc(k-18)]
         : 0.f;
}

// build lane's B-fragment for K-group KC (features KC*16+hi*8 .. +7), uniform code
template<int KC>
__device__ __forceinline__ bf16x8 mkfrag(const float* q, int hi) {
    uint32_t P[8];
#pragma unroll
    for (int j = 0; j < 8; j++) {
        union { __bf16 b[2]; uint32_t u; } pk;
        pk.b[0] = (__bf16)featv(KC*16 + 2*j,     q);
        pk.b[1] = (__bf16)featv(KC*16 + 2*j + 1, q);
        P[j] = pk.u;
    }
    union { uint32_t u[4]; bf16x8 v; } t;
#pragma unroll
    for (int j = 0; j < 4; j++) t.u[j] = hi ? P[4+j] : P[j];
    return t.v;
}

__device__ __forceinline__ void gload_lds16(const void* g, void* l) {
    __builtin_amdgcn_global_load_lds(
        (const __attribute__((address_space(1))) void*)g,
        (__attribute__((address_space(3))) void*)l, 16, 0, 0);
}

// one K-group: 4 A ds_reads + B build + 4 MFMA. KC/WSEL compile-time.
template<int KC, int WSEL>
__device__ __forceinline__ void kcstep(const char* bufc, const float* q, int hi,
                                       int l31, f32x16 (&acc)[4]) {
    bf16x8 A[4];
#pragma unroll
    for (int os = 0; os < 4; os++)
        A[os] = *(const bf16x8*)(bufc + (KC*2 + hi)*2048 + (((os^WSEL)*32) + l31)*16);
    bf16x8 tb = mkfrag<KC>(q, hi);
#pragma unroll
    for (int os = 0; os < 4; os++)
        acc[os] = __builtin_amdgcn_mfma_f32_32x32x16_bf16(A[os], tb, acc[os], 0, 0, 0);
}

// ---------- main: kc-split. Block = 256 thr = 4 waves = 2 pos-groups x 2
// kc-halves. Wave = 32 pos x 128 oc, kc in {2h, 2h+1} of EVERY channel
// (features k in [32h, 32h+32)). Both halves consume the SAME 16 KB channel
// slab -> LDS = 32 KB dbuf -> grid 1152 (4.5 blocks/CU, small tail), 4608
// waves, ~125 regs -> 4 waves/SIMD from 4 INDEPENDENT blocks: unsynchronized
// blocks cover each other's R-load stalls (r13's 512-thr block synchronized
// the stall phases). Feature build still once per (pos, channel, k-half).
// XOR ownership: local acc block os = global oc block (os ^ (h<<1)); combine
// with partner wave (wv^2) via LDS. All acc subscripts compile-time (rule #20).
// mfma_f32_32x32x16_bf16: A/B lane: row/col = lane&31, k = (lane>>5)*8+i;
// D: col = lane&31, row = (reg&3) + 8*(reg>>2) + 4*(lane>>5).
__global__ __launch_bounds__(256, 4) void socg_kc(const float* __restrict__ xp,
                                                  const __bf16* __restrict__ wb,
                                                  float* __restrict__ out) {
    __shared__ __align__(16) char sw[2][CHB];   // 32 KiB double-buffered slab

    const int tid  = threadIdx.x;
    const int lane = tid & 63;
    const int wv   = tid >> 6;      // 0..3
    const int g    = wv & 1;        // pos-group
    const int h    = wv >> 1;       // kc-half (wave-uniform)
    const int hi   = lane >> 5;
    const int l31  = lane & 31;
    const int wsel = h << 1;        // XOR remap of oc blocks per half

    const int bid  = blockIdx.x;    // 1152 = 8 imgs * 144 tiles
    const int bimg = bid & 7;       // XCD k -> image k (L2 locality)
    const int rem  = bid >> 3;      // 0..143
    const int h0   = (rem / 6) * 4; // block tile: 4 rows x 16 cols
    const int w0   = (rem % 6) * 16;

    const int r0 = h0 + g*2 + (l31 >> 4);
    const int c0 = w0 + (l31 & 15);

    const char* xbase = (const char*)(xp + (size_t)bimg*PIMG);
    const int voff0 = (r0*PW + c0) * 4;

    f32x16 acc[4];
#pragma unroll
    for (int os = 0; os < 4; os++)
#pragma unroll
        for (int r = 0; r < 16; r++) acc[os][r] = 0.f;

    // prologue: stage channel-0 slab (4 waves x 4 KB)
    {
        const char* wsrc = (const char*)wb;
#pragma unroll
        for (int i = 0; i < 4; i++) {
            const int m = i*4 + wv;
            gload_lds16(wsrc + m*1024 + lane*16, &sw[0][0] + m*1024);
        }
    }
    __syncthreads();

#pragma unroll 1
    for (int t = 0; t < 64; t++) {
        char* bufc = &sw[t & 1][0];
        // 1) R loads for this channel (needed soon; cross-block TLP covers latency)
        const char* xc = xbase + (size_t)t*(PCH*4);
        f32x4 R[3];
#pragma unroll
        for (int j = 0; j < 3; j++)
            R[j] = (f32x4)*(const f32x4u*)(xc + voff0 + j*(PW*4));
        // 2) stage next channel's slab (in flight until the end-of-step barrier)
        if (t + 1 < 64) {
            const char* wsrc = (const char*)wb + (size_t)(t + 1)*CHB;
            char* bufn = &sw[(t + 1) & 1][0];
#pragma unroll
            for (int i = 0; i < 4; i++) {
                const int m = i*4 + wv;
                gload_lds16(wsrc + m*1024 + lane*16, bufn + m*1024);
            }
        }
        // 3) window
        float q[9];
#pragma unroll
        for (int j = 0; j < 3; j++) {
            q[j*3 + 0] = R[j][0]; q[j*3 + 1] = R[j][1]; q[j*3 + 2] = R[j][2];
        }
        // 4) my two K-groups (wave-uniform branch on h; barrier stays outside)
        if (h == 0) {
            kcstep<0, 0>(bufc, q, hi, l31, acc);
            kcstep<1, 0>(bufc, q, hi, l31, acc);
        } else {
            kcstep<2, 2>(bufc, q, hi, l31, acc);
            kcstep<3, 2>(bufc, q, hi, l31, acc);
        }
        // 5) barrier: slab reads done + stage(t+1) landed
        __syncthreads();
    }

    // ---- kc-combine with partner wave (wv^2). Each wave STORES local acc[2],
    // acc[3] (partner's global oc blocks) and ADDS partner's contribution into
    // acc[0],acc[1]. All indices compile-time; lane*16 layout -> conflict-free.
    {
        char* lred = &sw[0][0];         // 4 waves x 8 KB = 32 KB (reuse slabs)
        char* my = lred + wv*8192;
#pragma unroll
        for (int g2 = 0; g2 < 8; g2++) {
            f32x4 v;
            v[0] = acc[2 + (g2>>2)][(g2&3)*4 + 0];
            v[1] = acc[2 + (g2>>2)][(g2&3)*4 + 1];
            v[2] = acc[2 + (g2>>2)][(g2&3)*4 + 2];
            v[3] = acc[2 + (g2>>2)][(g2&3)*4 + 3];
            *(f32x4*)(my + g2*1024 + lane*16) = v;
        }
        __syncthreads();
        const char* ot = lred + (wv ^ 2)*8192;
#pragma unroll
        for (int g2 = 0; g2 < 8; g2++) {
            f32x4 v = *(const f32x4*)(ot + g2*1024 + lane*16);
            acc[g2>>2][(g2&3)*4 + 0] += v[0];
            acc[g2>>2][(g2&3)*4 + 1] += v[1];
            acc[g2>>2][(g2&3)*4 + 2] += v[2];
            acc[g2>>2][(g2&3)*4 + 3] += v[3];
        }
    }

    // epilogue: write local acc[0],acc[1] -> global oc blocks (osl ^ wsel)
    const size_t obase = (size_t)bimg*OCH*HW*HW + (size_t)r0*HW + c0;
#pragma unroll
    for (int osl = 0; osl < 2; osl++) {
        const int gblk = osl ^ wsel;
#pragma unroll
        for (int r = 0; r < 16; r++) {
            const int oc = gblk*32 + (r & 3) + 8*(r >> 2) + 4*hi;
            out[obase + (size_t)oc*(HW*HW)] = acc[osl][r];
        }
    }
}

// ---------- fallback (no pad buffer): register-path kernel
__global__ __launch_bounds__(64, 3) void socg_fb(const float* __restrict__ x,
                                                 const __bf16* __restrict__ wb,
                                                 float* __restrict__ out) {
    const int lane = threadIdx.x;
    const int hi   = lane >> 5;
    const int l31  = lane & 31;

    const int bid  = blockIdx.x;
    const int bimg = bid / 288;
    const int rem  = bid - bimg * 288;
    const int h0   = (rem / 6) * 2;
    const int w0   = (rem % 6) * 16;

    const int hA = h0 + (l31 >> 4);
    const int wA = w0 + (l31 & 15);

    int   off[9];
    float msk[9];
#pragma unroll
    for (int rr = 0; rr < 3; rr++)
#pragma unroll
        for (int cc = 0; cc < 3; cc++) {
            int hh = hA - 1 + rr, ww = wA - 1 + cc;
            bool ok = ((unsigned)hh < HW) && ((unsigned)ww < HW);
            int hc = hh < 0 ? 0 : (hh > HW-1 ? HW-1 : hh);
            int wc = ww < 0 ? 0 : (ww > HW-1 ? HW-1 : ww);
            off[rr*3 + cc] = hc * HW + wc;
            msk[rr*3 + cc] = ok ? 1.f : 0.f;
        }

    const float* xb = x + (size_t)bimg * CIN * HW * HW;

    f32x16 acc[4];
#pragma unroll
    for (int os = 0; os < 4; os++)
#pragma unroll
        for (int r = 0; r < 16; r++) acc[os][r] = 0.f;

    float rA[9], rB[9];
#pragma unroll
    for (int i = 0; i < 9; i++) rA[i] = xb[off[i]];

    auto loadA = [&](bf16x8 (&A)[4], const __bf16* wc_, int kc) {
#pragma unroll
        for (int os = 0; os < 4; os++)
            A[os] = *(const bf16x8*)(wc_ + (kc*2 + hi)*1024 + (os*32 + l31)*8);
    };

    auto body = [&](float (&rc)[9], float (&rn)[9], int c) {
        const __bf16* wc_ = wb + (size_t)c * 8192;
        bf16x8 A0[4], A1[4], A2[4], A3[4];
        loadA(A0, wc_, 0);
        loadA(A1, wc_, 1);
        loadA(A2, wc_, 2);
        loadA(A3, wc_, 3);
        if (c + 1 < CIN) {
            const float* xn = xb + (size_t)(c + 1) * HW * HW;
#pragma unroll
            for (int i = 0; i < 9; i++) rn[i] = xn[off[i]];
        }
        float q[9];
#pragma unroll
        for (int i = 0; i < 9; i++) q[i] = rc[i] * msk[i];

        {
            bf16x8 tb = mkfrag<0>(q, hi);
#pragma unroll
            for (int os = 0; os < 4; os++)
                acc[os] = __builtin_amdgcn_mfma_f32_32x32x16_bf16(A0[os], tb, acc[os], 0, 0, 0);
        }
        {
            bf16x8 tb = mkfrag<1>(q, hi);
#pragma unroll
            for (int os = 0; os < 4; os++)
                acc[os] = __builtin_amdgcn_mfma_f32_32x32x16_bf16(A1[os], tb, acc[os], 0, 0, 0);
        }
        {
            bf16x8 tb = mkfrag<2>(q, hi);
#pragma unroll
            for (int os = 0; os < 4; os++)
                acc[os] = __builtin_amdgcn_mfma_f32_32x32x16_bf16(A2[os], tb, acc[os], 0, 0, 0);
        }
        {
            bf16x8 tb = mkfrag<3>(q, hi);
#pragma unroll
            for (int os = 0; os < 4; os++)
                acc[os] = __builtin_amdgcn_mfma_f32_32x32x16_bf16(A3[os], tb, acc[os], 0, 0, 0);
        }
    };

#pragma unroll 1
    for (int c2 = 0; c2 < CIN; c2 += 2) {
        body(rA, rB, c2);
        body(rB, rA, c2 + 1);
    }

#pragma unroll
    for (int os = 0; os < 4; os++)
#pragma unroll
        for (int r = 0; r < 16; r++) {
            int oc = os*32 + (r & 3) + 8*(r >> 2) + 4*hi;
            out[(((size_t)bimg*OCH + oc)*HW + hA)*HW + wA] = acc[os][r];
        }
}

extern "C" void kernel_launch(void* const* d_in, const int* in_sizes, int n_in,
                              void* d_out, int out_size, void* d_ws, size_t ws_size,
                              hipStream_t stream) {
    const float* x = (const float*)d_in[0];
    const float* w = (const float*)d_in[1];
    float* out = (float*)d_out;
    if (ws_size >= PAD_BYTES + WB_BYTES) {
        float* xpad = (float*)d_ws;
        __bf16* wbf = (__bf16*)((char*)d_ws + PAD_BYTES);
        hipLaunchKernelGGL(prep_pad, dim3(PAD_FLOATS/256), dim3(256), 0, stream, x, xpad);
        hipLaunchKernelGGL(prep_w, dim3(1024), dim3(256), 0, stream, w, wbf);
        hipLaunchKernelGGL(socg_kc, dim3(1152), dim3(256), 0, stream, xpad, wbf, out);
    } else {
        __bf16* wbf = (__bf16*)d_ws;
        hipLaunchKernelGGL(prep_w, dim3(1024), dim3(256), 0, stream, w, wbf);
        hipLaunchKernelGGL(socg_fb, dim3(2304), dim3(64), 0, stream, x, wbf, out);
    }
}